// Round 1
// 275.516 us; speedup vs baseline: 1.0193x; 1.0193x over previous
//
#include <hip/hip_runtime.h>
#include <hip/hip_bf16.h>

// Problem constants
#define Bc   2
#define Nc   4096
#define Hc   4
#define HIDc 256
#define VDc  64

typedef short s8v  __attribute__((ext_vector_type(8)));
typedef float f4v  __attribute__((ext_vector_type(4)));

// ---------------------------------------------------------------------------
// K1: V[b,h,n,k] = sum_j x[b,n,j] * W[h,j,k]; store TRANSPOSED as VT[b,h,k,n] bf16
// grid = B*H*(N/64) = 512 blocks, 256 threads.  (unchanged this round)
// ---------------------------------------------------------------------------
#define XSP 260

__global__ __launch_bounds__(256) void value_kernel(
    const float* __restrict__ x, const float* __restrict__ wgt,
    unsigned short* __restrict__ vt_g)
{
    __shared__ float xs[64 * XSP];           // 66.6 KB
    __shared__ unsigned short ob[64 * 64];   // 8 KB: out tile [k][n] bf16

    int t  = threadIdx.x;
    int bid = blockIdx.x;
    int nt = bid & 63;
    int h  = (bid >> 6) & 3;
    int b  = bid >> 8;
    int n0 = nt * 64;

    const float* xg = x + ((size_t)b * Nc + n0) * HIDc;
    #pragma unroll
    for (int i = 0; i < 16; i++) {
        int id = t + i * 256;
        int row = id >> 6, ch = id & 63;
        *(float4*)&xs[row * XSP + ch * 4] = ((const float4*)xg)[id];
    }
    __syncthreads();

    int k4 = t & 15;      // float4-group of k (k = k4*4 .. +3)
    int ns = t >> 4;      // n sub-row
    const float4* wg4 = (const float4*)(wgt + (size_t)h * HIDc * VDc);

    float4 acc[4];
    #pragma unroll
    for (int i = 0; i < 4; i++) acc[i] = (float4){0.f, 0.f, 0.f, 0.f};

    for (int j = 0; j < HIDc; j += 4) {
        float4 w0 = wg4[(j + 0) * 16 + k4];
        float4 w1 = wg4[(j + 1) * 16 + k4];
        float4 w2 = wg4[(j + 2) * 16 + k4];
        float4 w3 = wg4[(j + 3) * 16 + k4];
        #pragma unroll
        for (int i = 0; i < 4; i++) {
            float4 xv = *(const float4*)&xs[(ns + i * 16) * XSP + j];
            acc[i].x += xv.x * w0.x + xv.y * w1.x + xv.z * w2.x + xv.w * w3.x;
            acc[i].y += xv.x * w0.y + xv.y * w1.y + xv.z * w2.y + xv.w * w3.y;
            acc[i].z += xv.x * w0.z + xv.y * w1.z + xv.z * w2.z + xv.w * w3.z;
            acc[i].w += xv.x * w0.w + xv.y * w1.w + xv.z * w2.w + xv.w * w3.w;
        }
    }
    #pragma unroll
    for (int i = 0; i < 4; i++) {
        int nn = ns + i * 16;
        float a[4] = {acc[i].x, acc[i].y, acc[i].z, acc[i].w};
        #pragma unroll
        for (int c = 0; c < 4; c++) {
            __hip_bfloat16 hb = __float2bfloat16(a[c]);
            ob[(k4 * 4 + c) * 64 + nn] = *(unsigned short*)&hb;
        }
    }
    __syncthreads();

    unsigned short* vg = vt_g + (((size_t)b * Hc + h) * VDc) * Nc + n0;
    #pragma unroll
    for (int i = 0; i < 16; i++) {
        int idx = t + i * 256;
        int kk = idx >> 6, nn = idx & 63;
        vg[(size_t)kk * Nc + nn] = ob[idx];   // coalesced over nn
    }
}

// ---------------------------------------------------------------------------
// K2: per-row exact 30th percentile (ranks 1228/1229) + row min.
// R5: WINDOWED histogram. m_dist ~ U[0,1) exactly, so ranks 1228/1229 of 4096
// lie in [0.25,0.35] with ~7 sigma margin -> histogram only ~410 in-window
// values (10x fewer LDS atomics than the full 4096, near-zero bank collisions).
// Below-window count via shuffle reduce (no atomics). Guaranteed-exact
// fallback: widen window to [0,1.001) and redo (statistically never taken).
// Result is bit-identical to the full-histogram version.
// ---------------------------------------------------------------------------
__global__ __launch_bounds__(256) void thresh_kernel(
    const float* __restrict__ m_dist,
    float* __restrict__ thr_out, float* __restrict__ min_out)
{
    __shared__ unsigned int hist[1024];
    __shared__ float wredf[4];
    __shared__ unsigned int wsum[4];
    __shared__ unsigned int wscan[4];
    __shared__ int b0s, b1s;
    __shared__ unsigned int c0s;
    __shared__ unsigned int ncand;
    __shared__ float cand[256];
    __shared__ float s0s, s1s;

    int t = threadIdx.x;
    size_t rowid = blockIdx.x;
    const float* row = m_dist + rowid * Nc;

    float4 vals[4];
    float lmin = 1e30f;
    #pragma unroll
    for (int i = 0; i < 4; i++) {
        float4 v = ((const float4*)row)[t + i * 256];
        vals[i] = v;
        lmin = fminf(lmin, fminf(fminf(v.x, v.y), fminf(v.z, v.w)));
    }
    // min reduce
    #pragma unroll
    for (int o = 32; o > 0; o >>= 1) lmin = fminf(lmin, __shfl_xor(lmin, o));
    if ((t & 63) == 0) wredf[t >> 6] = lmin;
    // (covered by barriers inside the select loop before use)

    const unsigned int R0 = 1228u, R1 = 1229u;   // 0-indexed order stats
    float wlo = 0.25f, whi = 0.35f;
    int b0 = 0, b1 = 0;
    unsigned int C0 = 0;

    for (;;) {
        float wscale = 1024.0f / (whi - wlo);

        for (int i = t; i < 1024; i += 256) hist[i] = 0u;
        if (t == 0) ncand = 0u;
        __syncthreads();

        // count below-window + histogram the in-window values
        unsigned int cb = 0;
        #pragma unroll
        for (int i = 0; i < 4; i++) {
            float a[4] = {vals[i].x, vals[i].y, vals[i].z, vals[i].w};
            #pragma unroll
            for (int j = 0; j < 4; j++) {
                float v = a[j];
                if (v < wlo) {
                    cb++;
                } else {
                    int bx = (int)((v - wlo) * wscale);
                    if (bx < 1024) atomicAdd(&hist[bx], 1u);
                }
            }
        }
        #pragma unroll
        for (int o = 32; o > 0; o >>= 1) cb += __shfl_xor(cb, o);
        if ((t & 63) == 0) wsum[t >> 6] = cb;
        __syncthreads();
        unsigned int Cb = wsum[0] + wsum[1] + wsum[2] + wsum[3];

        // scan: thread t owns bins 4t..4t+3
        unsigned int c[4], csum = 0;
        #pragma unroll
        for (int j = 0; j < 4; j++) { c[j] = hist[t * 4 + j]; csum += c[j]; }
        unsigned int inc = csum;
        #pragma unroll
        for (int o = 1; o < 64; o <<= 1) {
            unsigned int nv = __shfl_up(inc, o);
            if ((t & 63) >= o) inc += nv;
        }
        if ((t & 63) == 63) wscan[t >> 6] = inc;
        __syncthreads();
        unsigned int wpref = 0;
        for (int wv = 0; wv < (t >> 6); wv++) wpref += wscan[wv];
        unsigned int T = wscan[0] + wscan[1] + wscan[2] + wscan[3];
        unsigned int P = Cb + wpref + inc - csum;   // global rank of first value in bin 4t

        unsigned int cum = P;
        #pragma unroll
        for (int j = 0; j < 4; j++) {
            unsigned int lo = cum, hi = cum + c[j];
            if (R0 >= lo && R0 < hi) { b0s = t * 4 + j; c0s = lo; }
            if (R1 >= lo && R1 < hi) { b1s = t * 4 + j; }
            cum = hi;
        }
        __syncthreads();

        if (Cb <= R0 && R1 < Cb + T) { b0 = b0s; b1 = b1s; C0 = c0s; break; }
        // fallback (never taken statistically): full-range pass, guaranteed hit
        wlo = 0.0f; whi = 1.001f;
    }

    // gather candidates in bins [b0, b1]
    float wscale = 1024.0f / (whi - wlo);
    #pragma unroll
    for (int i = 0; i < 4; i++) {
        float a[4] = {vals[i].x, vals[i].y, vals[i].z, vals[i].w};
        #pragma unroll
        for (int j = 0; j < 4; j++) {
            float v = a[j];
            if (v >= wlo) {
                int bx = (int)((v - wlo) * wscale);
                if (bx >= b0 && bx <= b1) {
                    unsigned int p = atomicAdd(&ncand, 1u);
                    if (p < 256u) cand[p] = v;
                }
            }
        }
    }
    __syncthreads();
    unsigned int nc = min(ncand, 256u);
    if ((unsigned int)t < nc) {
        float v = cand[t];
        unsigned int rk = C0;
        for (unsigned int j = 0; j < nc; j++) {
            float u = cand[j];
            rk += (u < v || (u == v && j < (unsigned int)t)) ? 1u : 0u;
        }
        if (rk == R0) s0s = v;
        if (rk == R1) s1s = v;
    }
    __syncthreads();
    if (t == 0) {
        thr_out[rowid] = 0.5f * (s0s + s1s);  // any value in [s0,s1) gives same mask
        min_out[rowid] = fminf(fminf(wredf[0], wredf[1]), fminf(wredf[2], wredf[3]));
    }
}

// ---------------------------------------------------------------------------
// K3: fused mask + softmax-numerator + PV (bf16 MFMA), split-K over j.
// grid = S * B * (N/32) blocks, 512 threads (8 waves: wave = (rowhalf, head)).
// R5 change: vt staging via __builtin_amdgcn_global_load_lds width=16 with the
// XOR swizzle moved to the GLOBAL SOURCE side (linear LDS dest, m173 pattern):
// per-wave LDS dest for [rrow][vch] is exactly base + lane*16 bytes, source
// chunk = (lane&7) ^ (lane>>3). Deletes 4 global->VGPR loads + 4 ds_write_b128
// per thread/iter and frees ~16 VGPRs under the 64-VGPR (512,8) cap.
// ms staging stays register-based (fuses the head-independent premask:
// masked d -> 3e38 so exp2(fma(d,cc,-mn*cc)) = 0 exactly).
// XOR-swizzled unpadded LDS: ms 8KB + vt 32KB = 40960B -> 4 blocks/CU.
// ---------------------------------------------------------------------------
#define NT 32
#define JT 64
#define BIGF 3.0e38f

__global__ __launch_bounds__(512, 8) void attn_kernel(
    const float* __restrict__ m_dist, const float* __restrict__ rr,
    const unsigned short* __restrict__ vt_g,
    const float* __restrict__ thr_g, const float* __restrict__ min_g,
    float* __restrict__ Op, float* __restrict__ Zp, int jlen)
{
    __shared__ float ms[NT * 64];                 // 8 KB, chunk c at c^(row&15)
    __shared__ unsigned short vt[Hc * VDc * 64];  // 32 KB, chunk c at c^(row&7)

    int t = threadIdx.x;
    const int nblk = Bc * (Nc / NT);        // 256
    int js = blockIdx.x / nblk;
    int rb = blockIdx.x - js * nblk;
    int b  = rb >> 7;                       // Nc/NT = 128 row-tiles
    int n0 = (rb & 127) * NT;
    int j0 = js * jlen;

    int lane = t & 63, q = lane >> 4, m16 = lane & 15;
    int w = t >> 6;                         // wave 0..7
    int h = w & 3, rh = w >> 2;
    int row = rh * 16 + m16;                // local A-row this lane owns

    float mn = min_g[b * Nc + n0 + row];
    float rv = rr[h];
    float cc = -(rv * rv) * 1.4426950408889634f;   // -r^2 * log2(e)
    float nmncc = -mn * cc;                        // w = exp2(fma(d, cc, nmncc))

    f4v acc[4];
    #pragma unroll
    for (int ct = 0; ct < 4; ct++) acc[ct] = (f4v){0.f, 0.f, 0.f, 0.f};
    float zacc = 0.f;

    const float* mbase = m_dist + ((size_t)b * Nc + n0) * Nc + j0;
    const unsigned short* vtb = vt_g + ((size_t)b * Hc * VDc) * Nc + j0;

    // ms staging map (swizzled LDS destination, register path w/ premask)
    int mrow = t >> 4, mch = t & 15;        // ms: 32 rows x 16 float4-chunks
    int msw  = mrow * 64 + ((mch ^ (mrow & 15)) << 2);
    float thm = thr_g[b * Nc + n0 + mrow];  // staging-row threshold (premask)

    // vt DMA staging map: lane -> row (w*8 + lane>>3 + i*64), lds chunk lane&7.
    // LDS linear addr = w*1024 + lane*16 bytes (wave-uniform base + lane*16).
    // Source chunk pre-swizzled: (lane&7) ^ (rrow&7), and rrow&7 == lane>>3.
    int srowl   = lane >> 3;                        // 0..7
    int schunk8 = ((lane & 7) ^ srowl) * 8;         // ushort offset in row
    unsigned short* vt_wbase = &vt[(w * 8) * 64];   // uniform per wave

    // A-read swizzled chunk offsets for this lane (row&15 == m16)
    int a00 = row * 64 + (((q * 2 + 0) ^ m16) << 2);       // ks=0
    int a01 = row * 64 + (((q * 2 + 1) ^ m16) << 2);
    int a10 = row * 64 + (((8 + q * 2 + 0) ^ m16) << 2);   // ks=1
    int a11 = row * 64 + (((8 + q * 2 + 1) ^ m16) << 2);

    for (int jt = 0; jt < jlen; jt += JT) {
        // stage vt (256 rows x 64 j bf16): 4 x global_load_lds dwordx4 / thread
        #pragma unroll
        for (int i = 0; i < 4; i++) {
            int rrow = w * 8 + srowl + i * 64;
            __builtin_amdgcn_global_load_lds(
                (const __attribute__((address_space(1))) void*)
                    (vtb + (size_t)rrow * Nc + jt + schunk8),
                (__attribute__((address_space(3))) void*)
                    (vt_wbase + i * 64 * 64),
                16, 0, 0);
        }
        // stage ms (32 x 64 f32): 1 float4/thread, PREMASKED, swizzled dest
        {
            float4 v = *(const float4*)(mbase + (size_t)mrow * Nc + jt + mch * 4);
            v.x = (v.x <= thm) ? v.x : BIGF;
            v.y = (v.y <= thm) ? v.y : BIGF;
            v.z = (v.z <= thm) ? v.z : BIGF;
            v.w = (v.w <= thm) ? v.w : BIGF;
            *(float4*)&ms[msw] = v;
        }
        __syncthreads();

        const unsigned short* vb = &vt[(h * VDc) * 64];
        #pragma unroll
        for (int ks = 0; ks < 2; ks++) {
            float4 a0 = *(const float4*)&ms[ks ? a10 : a00];
            float4 a1 = *(const float4*)&ms[ks ? a11 : a01];
            float w0 = __builtin_amdgcn_exp2f(__builtin_fmaf(a0.x, cc, nmncc));
            float w1 = __builtin_amdgcn_exp2f(__builtin_fmaf(a0.y, cc, nmncc));
            float w2 = __builtin_amdgcn_exp2f(__builtin_fmaf(a0.z, cc, nmncc));
            float w3 = __builtin_amdgcn_exp2f(__builtin_fmaf(a0.w, cc, nmncc));
            float w4 = __builtin_amdgcn_exp2f(__builtin_fmaf(a1.x, cc, nmncc));
            float w5 = __builtin_amdgcn_exp2f(__builtin_fmaf(a1.y, cc, nmncc));
            float w6 = __builtin_amdgcn_exp2f(__builtin_fmaf(a1.z, cc, nmncc));
            float w7 = __builtin_amdgcn_exp2f(__builtin_fmaf(a1.w, cc, nmncc));
            zacc += ((w0 + w1) + (w2 + w3)) + ((w4 + w5) + (w6 + w7));
            union { s8v v; __hip_bfloat162 h2[4]; } afu;
            afu.h2[0] = __float22bfloat162_rn((float2){w0, w1});
            afu.h2[1] = __float22bfloat162_rn((float2){w2, w3});
            afu.h2[2] = __float22bfloat162_rn((float2){w4, w5});
            afu.h2[3] = __float22bfloat162_rn((float2){w6, w7});
            #pragma unroll
            for (int ct = 0; ct < 4; ct++) {
                int brow = ct * 16 + m16;
                s8v bf = *(const s8v*)(vb + brow * 64 + (((ks * 4 + q) ^ (m16 & 7)) << 3));
                acc[ct] = __builtin_amdgcn_mfma_f32_16x16x32_bf16(afu.v, bf, acc[ct], 0, 0, 0);
            }
        }
        __syncthreads();
    }

    // Z: lanes sharing m16 across q (xor 16, 32)
    zacc += __shfl_xor(zacc, 16);
    zacc += __shfl_xor(zacc, 32);
    if (q == 0)
        Zp[(((size_t)js * Bc + b) * Hc + h) * Nc + n0 + row] = zacc;

    // partial O: D row = q*4+rg (within the 16), col = ct*16+m16
    #pragma unroll
    for (int ct = 0; ct < 4; ct++) {
        #pragma unroll
        for (int rg = 0; rg < 4; rg++) {
            int nl = rh * 16 + q * 4 + rg;
            Op[(((size_t)js * Bc + b) * Nc + n0 + nl) * HIDc + h * VDc + ct * 16 + m16]
                = acc[ct][rg];
        }
    }
}

// ---------------------------------------------------------------------------
// K4: combine split-K partials, normalize, exact GELU. f32x4 per thread.
// grid = B*N*HID/1024 = 2048 blocks x 256.  (unchanged this round)
// ---------------------------------------------------------------------------
__global__ __launch_bounds__(256) void combine_kernel(
    const float* __restrict__ Op, const float* __restrict__ Zp,
    float* __restrict__ out, int S)
{
    int g = blockIdx.x * 256 + threadIdx.x;       // float4 index
    int c4 = g & 63;
    int n  = (g >> 6) & (Nc - 1);
    int b  = g >> 18;                             // 64 * 4096 = 2^18
    int h  = c4 >> 4;

    float z = 0.f;
    float4 v = {0.f, 0.f, 0.f, 0.f};
    for (int s = 0; s < S; s++) {
        z += Zp[(((size_t)s * Bc + b) * Hc + h) * Nc + n];
        float4 p = *(const float4*)&Op[(((size_t)s * Bc + b) * Nc + n) * HIDc + c4 * 4];
        v.x += p.x; v.y += p.y; v.z += p.z; v.w += p.w;
    }
    float iz = 1.0f / z;
    float4 o;
    float u;
    u = v.x * iz; o.x = 0.5f * u * (1.0f + erff(u * 0.7071067811865476f));
    u = v.y * iz; o.y = 0.5f * u * (1.0f + erff(u * 0.7071067811865476f));
    u = v.z * iz; o.z = 0.5f * u * (1.0f + erff(u * 0.7071067811865476f));
    u = v.w * iz; o.w = 0.5f * u * (1.0f + erff(u * 0.7071067811865476f));
    *(float4*)&out[(((size_t)b * Nc + n) * HIDc) + c4 * 4] = o;
}

// ---------------------------------------------------------------------------
extern "C" void kernel_launch(void* const* d_in, const int* in_sizes, int n_in,
                              void* d_out, int out_size, void* d_ws, size_t ws_size,
                              hipStream_t stream) {
    const float* m_dist = (const float*)d_in[0];
    const float* x      = (const float*)d_in[1];
    const float* r      = (const float*)d_in[2];
    const float* weight = (const float*)d_in[3];
    float* out = (float*)d_out;

    char* ws = (char*)d_ws;
    const size_t MB = 1024 * 1024;
    unsigned short* vt = (unsigned short*)ws;            // 4 MiB bf16 VT
    float* thr = (float*)(ws + 4 * MB);                  // 32 KiB
    float* mn  = (float*)(ws + 4 * MB + 32 * 1024);      // 32 KiB
    float* Zp  = (float*)(ws + 4 * MB + 64 * 1024);      // up to 512 KiB
    float* Op  = (float*)(ws + 5 * MB);                  // S * 8 MiB

    // split factor: prefer 4 (needs 37 MiB ws), else 2, else 1
    int S = 4;
    if (ws_size < 5 * MB + 4 * (size_t)(Bc * Nc * HIDc * 4)) S = 2;
    if (ws_size < 5 * MB + 2 * (size_t)(Bc * Nc * HIDc * 4)) S = 1;
    int jlen = Nc / S;

    value_kernel<<<512, 256, 0, stream>>>(x, weight, vt);
    thresh_kernel<<<Bc * Nc, 256, 0, stream>>>(m_dist, thr, mn);
    attn_kernel<<<S * Bc * (Nc / NT), 512, 0, stream>>>(m_dist, r, vt, thr, mn, Op, Zp, jlen);
    combine_kernel<<<(Bc * Nc * HIDc) / 1024, 256, 0, stream>>>(Op, Zp, out, S);
}

// Round 2
// 266.808 us; speedup vs baseline: 1.0525x; 1.0326x over previous
//
#include <hip/hip_runtime.h>
#include <hip/hip_bf16.h>

// Problem constants
#define Bc   2
#define Nc   4096
#define Hc   4
#define HIDc 256
#define VDc  64

typedef short s8v  __attribute__((ext_vector_type(8)));
typedef float f4v  __attribute__((ext_vector_type(4)));

static __device__ __forceinline__ unsigned short bf16bits(float f) {
    __hip_bfloat16 h = __float2bfloat16(f);
    return *(unsigned short*)&h;
}

// ---------------------------------------------------------------------------
// K0 (prep): split x and W into bf16 hi/lo pairs.
//  - x -> xh,xl [B][N][HID] bf16 (coalesced, 8 elems/thread)
//  - W -> wh,wl in MFMA-A-fragment-linear layout: for (h,kt,jc), lane l, i:
//      elem = W[jc*32+(l>>4)*8+i][kt*16+(l&15)]  stored at
//      ((h*4+kt)*8+jc)*512 + l*8 + i   (so K1 reads one coalesced b128/lane)
// grid = 1024 (x) + 128 (W) blocks x 256.
// ---------------------------------------------------------------------------
__global__ __launch_bounds__(256) void prep_kernel(
    const float* __restrict__ x, const float* __restrict__ wgt,
    unsigned short* __restrict__ xh, unsigned short* __restrict__ xl,
    unsigned short* __restrict__ wh, unsigned short* __restrict__ wl)
{
    int t = threadIdx.x, bid = blockIdx.x;
    if (bid < 1024) {
        size_t g = ((size_t)bid * 256 + t) * 8;
        float4 v0 = *(const float4*)(x + g);
        float4 v1 = *(const float4*)(x + g + 4);
        float f[8] = {v0.x, v0.y, v0.z, v0.w, v1.x, v1.y, v1.z, v1.w};
        union { s8v v; unsigned short u[8]; } hs, ls;
        #pragma unroll
        for (int i = 0; i < 8; i++) {
            __hip_bfloat16 hb = __float2bfloat16(f[i]);
            float hf = __bfloat162float(hb);
            hs.u[i] = *(unsigned short*)&hb;
            ls.u[i] = bf16bits(f[i] - hf);
        }
        *(s8v*)(xh + g) = hs.v;
        *(s8v*)(xl + g) = ls.v;
    } else {
        int b2 = bid - 1024;              // 0..127
        int h  = b2 >> 5;
        int kt = (b2 >> 3) & 3;
        int jc = b2 & 7;
        int lane = t >> 2, ii = t & 3;
        #pragma unroll
        for (int u = 0; u < 2; u++) {
            int i = ii * 2 + u;
            int j = jc * 32 + (lane >> 4) * 8 + i;
            int k = kt * 16 + (lane & 15);
            float v = wgt[((size_t)h * HIDc + j) * VDc + k];
            __hip_bfloat16 hb = __float2bfloat16(v);
            float hf = __bfloat162float(hb);
            size_t o = ((((size_t)h * 4 + kt) * 8 + jc) * 64 + lane) * 8 + i;
            wh[o] = *(unsigned short*)&hb;
            wl[o] = bf16bits(v - hf);
        }
    }
}

// ---------------------------------------------------------------------------
// K1: V^T via MFMA, 3-term bf16 split (Ah*Bh + Al*Bh + Ah*Bl ~ f32-accurate).
// D[row=k][col=n] = sum_j W[j][k] * x[n][j]  ->  VT[b,h,k,n] bf16 directly.
// grid = B*H*(N/64) = 512 blocks x 256 (4 waves; wave w owns n-tile w).
// Per wave: 8 j-chunks x (2 B-frag b128 + 8 A-frag b128 + 12 MFMA).
// ---------------------------------------------------------------------------
__global__ __launch_bounds__(256) void value_kernel(
    const unsigned short* __restrict__ xh, const unsigned short* __restrict__ xl,
    const unsigned short* __restrict__ wh, const unsigned short* __restrict__ wl,
    unsigned short* __restrict__ vt_g)
{
    int t  = threadIdx.x;
    int bid = blockIdx.x;
    int nt = bid & 63;
    int h  = (bid >> 6) & 3;
    int b  = bid >> 8;
    int n0 = nt * 64;

    int w = t >> 6, lane = t & 63, q4 = lane >> 4, m16 = lane & 15;
    int nb = n0 + w * 16;

    const unsigned short* xhp = xh + ((size_t)(b * Nc + nb + m16)) * HIDc + q4 * 8;
    const unsigned short* xlp = xl + ((size_t)(b * Nc + nb + m16)) * HIDc + q4 * 8;

    f4v acc[4];
    #pragma unroll
    for (int kt = 0; kt < 4; kt++) acc[kt] = (f4v){0.f, 0.f, 0.f, 0.f};

    #pragma unroll
    for (int jc = 0; jc < 8; jc++) {
        s8v bh = *(const s8v*)(xhp + jc * 32);
        s8v bl = *(const s8v*)(xlp + jc * 32);
        #pragma unroll
        for (int kt = 0; kt < 4; kt++) {
            size_t ao = (((size_t)(h * 4 + kt) * 8 + jc) << 9) + lane * 8;
            s8v ah = *(const s8v*)(wh + ao);
            s8v al = *(const s8v*)(wl + ao);
            acc[kt] = __builtin_amdgcn_mfma_f32_16x16x32_bf16(ah, bh, acc[kt], 0, 0, 0);
            acc[kt] = __builtin_amdgcn_mfma_f32_16x16x32_bf16(al, bh, acc[kt], 0, 0, 0);
            acc[kt] = __builtin_amdgcn_mfma_f32_16x16x32_bf16(ah, bl, acc[kt], 0, 0, 0);
        }
    }

    unsigned short* vg = vt_g + (((size_t)b * Hc + h) * VDc) * Nc;
    #pragma unroll
    for (int kt = 0; kt < 4; kt++) {
        #pragma unroll
        for (int rg = 0; rg < 4; rg++) {
            int k = kt * 16 + q4 * 4 + rg;
            vg[(size_t)k * Nc + nb + m16] = bf16bits(acc[kt][rg]);
        }
    }
}

// ---------------------------------------------------------------------------
// K2: per-row exact 30th percentile (ranks 1228/1229) + row min.
// Windowed histogram on [0.25,0.35] (ranks of U[0,1) land there w/ ~7 sigma
// margin); exact full-range fallback pass if not. Unchanged from R1.
// ---------------------------------------------------------------------------
__global__ __launch_bounds__(256) void thresh_kernel(
    const float* __restrict__ m_dist,
    float* __restrict__ thr_out, float* __restrict__ min_out)
{
    __shared__ unsigned int hist[1024];
    __shared__ float wredf[4];
    __shared__ unsigned int wsum[4];
    __shared__ unsigned int wscan[4];
    __shared__ int b0s, b1s;
    __shared__ unsigned int c0s;
    __shared__ unsigned int ncand;
    __shared__ float cand[256];
    __shared__ float s0s, s1s;

    int t = threadIdx.x;
    size_t rowid = blockIdx.x;
    const float* row = m_dist + rowid * Nc;

    float4 vals[4];
    float lmin = 1e30f;
    #pragma unroll
    for (int i = 0; i < 4; i++) {
        float4 v = ((const float4*)row)[t + i * 256];
        vals[i] = v;
        lmin = fminf(lmin, fminf(fminf(v.x, v.y), fminf(v.z, v.w)));
    }
    #pragma unroll
    for (int o = 32; o > 0; o >>= 1) lmin = fminf(lmin, __shfl_xor(lmin, o));
    if ((t & 63) == 0) wredf[t >> 6] = lmin;

    const unsigned int R0 = 1228u, R1 = 1229u;
    float wlo = 0.25f, whi = 0.35f;
    int b0 = 0, b1 = 0;
    unsigned int C0 = 0;

    for (;;) {
        float wscale = 1024.0f / (whi - wlo);

        for (int i = t; i < 1024; i += 256) hist[i] = 0u;
        if (t == 0) ncand = 0u;
        __syncthreads();

        unsigned int cb = 0;
        #pragma unroll
        for (int i = 0; i < 4; i++) {
            float a[4] = {vals[i].x, vals[i].y, vals[i].z, vals[i].w};
            #pragma unroll
            for (int j = 0; j < 4; j++) {
                float v = a[j];
                if (v < wlo) {
                    cb++;
                } else {
                    int bx = (int)((v - wlo) * wscale);
                    if (bx < 1024) atomicAdd(&hist[bx], 1u);
                }
            }
        }
        #pragma unroll
        for (int o = 32; o > 0; o >>= 1) cb += __shfl_xor(cb, o);
        if ((t & 63) == 0) wsum[t >> 6] = cb;
        __syncthreads();
        unsigned int Cb = wsum[0] + wsum[1] + wsum[2] + wsum[3];

        unsigned int c[4], csum = 0;
        #pragma unroll
        for (int j = 0; j < 4; j++) { c[j] = hist[t * 4 + j]; csum += c[j]; }
        unsigned int inc = csum;
        #pragma unroll
        for (int o = 1; o < 64; o <<= 1) {
            unsigned int nv = __shfl_up(inc, o);
            if ((t & 63) >= o) inc += nv;
        }
        if ((t & 63) == 63) wscan[t >> 6] = inc;
        __syncthreads();
        unsigned int wpref = 0;
        for (int wv = 0; wv < (t >> 6); wv++) wpref += wscan[wv];
        unsigned int T = wscan[0] + wscan[1] + wscan[2] + wscan[3];
        unsigned int P = Cb + wpref + inc - csum;

        unsigned int cum = P;
        #pragma unroll
        for (int j = 0; j < 4; j++) {
            unsigned int lo = cum, hi = cum + c[j];
            if (R0 >= lo && R0 < hi) { b0s = t * 4 + j; c0s = lo; }
            if (R1 >= lo && R1 < hi) { b1s = t * 4 + j; }
            cum = hi;
        }
        __syncthreads();

        if (Cb <= R0 && R1 < Cb + T) { b0 = b0s; b1 = b1s; C0 = c0s; break; }
        wlo = 0.0f; whi = 1.001f;
    }

    float wscale = 1024.0f / (whi - wlo);
    #pragma unroll
    for (int i = 0; i < 4; i++) {
        float a[4] = {vals[i].x, vals[i].y, vals[i].z, vals[i].w};
        #pragma unroll
        for (int j = 0; j < 4; j++) {
            float v = a[j];
            if (v >= wlo) {
                int bx = (int)((v - wlo) * wscale);
                if (bx >= b0 && bx <= b1) {
                    unsigned int p = atomicAdd(&ncand, 1u);
                    if (p < 256u) cand[p] = v;
                }
            }
        }
    }
    __syncthreads();
    unsigned int nc = min(ncand, 256u);
    if ((unsigned int)t < nc) {
        float v = cand[t];
        unsigned int rk = C0;
        for (unsigned int j = 0; j < nc; j++) {
            float u = cand[j];
            rk += (u < v || (u == v && j < (unsigned int)t)) ? 1u : 0u;
        }
        if (rk == R0) s0s = v;
        if (rk == R1) s1s = v;
    }
    __syncthreads();
    if (t == 0) {
        thr_out[rowid] = 0.5f * (s0s + s1s);
        min_out[rowid] = fminf(fminf(wredf[0], wredf[1]), fminf(wredf[2], wredf[3]));
    }
}

// ---------------------------------------------------------------------------
// K3: fused mask + softmax-numerator + PV (bf16 MFMA), split-K over j.
// R2: NT 32 -> 64 with 1024 threads (16 waves: wave = (rowquad rq, head h)).
// Halves the vt re-read traffic (each staged 32KB vt tile now feeds 64 rows)
// and halves blocks to 512 (2/CU at 48KB LDS, 32 waves/CU).
// vt staged by global_load_lds w/ source-side swizzle (linear LDS dest);
// ms staged via registers (fuses head-independent premask: masked d -> 3e38).
// ---------------------------------------------------------------------------
#define NT 64
#define JT 64
#define BIGF 3.0e38f

__global__ __launch_bounds__(1024, 8) void attn_kernel(
    const float* __restrict__ m_dist, const float* __restrict__ rr,
    const unsigned short* __restrict__ vt_g,
    const float* __restrict__ thr_g, const float* __restrict__ min_g,
    float* __restrict__ Op, float* __restrict__ Zp, int jlen)
{
    __shared__ float ms[NT * 64];                 // 16 KB, chunk c at c^(row&15)
    __shared__ unsigned short vt[Hc * VDc * 64];  // 32 KB, chunk c at c^(row&7)

    int t = threadIdx.x;
    const int nblk = Bc * (Nc / NT);        // 128
    int js = blockIdx.x / nblk;
    int rb = blockIdx.x - js * nblk;
    int b  = rb >> 6;                       // Nc/NT = 64 row-tiles
    int n0 = (rb & 63) * NT;
    int j0 = js * jlen;

    int lane = t & 63, q = lane >> 4, m16 = lane & 15;
    int w = t >> 6;                         // wave 0..15
    int h = w & 3, rq = w >> 2;             // head, row-quad
    int row = rq * 16 + m16;                // local A-row this lane owns (0..63)

    float mn = min_g[b * Nc + n0 + row];
    float rv = rr[h];
    float cc = -(rv * rv) * 1.4426950408889634f;   // -r^2 * log2(e)
    float nmncc = -mn * cc;                        // w = exp2(fma(d, cc, nmncc))

    f4v acc[4];
    #pragma unroll
    for (int ct = 0; ct < 4; ct++) acc[ct] = (f4v){0.f, 0.f, 0.f, 0.f};
    float zacc = 0.f;

    const float* mbase = m_dist + ((size_t)b * Nc + n0) * Nc + j0;
    const unsigned short* vtb = vt_g + ((size_t)b * Hc * VDc) * Nc + j0;

    // ms staging map (swizzled LDS destination, register path w/ premask)
    int mrow = t >> 4, mch = t & 15;        // ms: 64 rows x 16 float4-chunks
    int msw  = mrow * 64 + ((mch ^ (mrow & 15)) << 2);
    float thm = thr_g[b * Nc + n0 + mrow];  // staging-row threshold (premask)

    // vt DMA staging map (2 DMA/thread): row r = (t>>3) + i*128, phys chunk t&7,
    // logical source chunk (t&7) ^ (r&7); r&7 == (t>>3)&7 (128 = 0 mod 8).
    int schunk8 = ((t & 7) ^ ((t >> 3) & 7)) * 8;   // ushort offset in row
    unsigned short* vt_wbase = &vt[(w * 8) * 64];   // uniform per wave

    // A-read swizzled chunk offsets for this lane (row&15 == m16)
    int a00 = row * 64 + (((q * 2 + 0) ^ m16) << 2);       // ks=0
    int a01 = row * 64 + (((q * 2 + 1) ^ m16) << 2);
    int a10 = row * 64 + (((8 + q * 2 + 0) ^ m16) << 2);   // ks=1
    int a11 = row * 64 + (((8 + q * 2 + 1) ^ m16) << 2);

    for (int jt = 0; jt < jlen; jt += JT) {
        // stage vt (256 rows x 64 j bf16): 2 x global_load_lds dwordx4 / thread
        #pragma unroll
        for (int i = 0; i < 2; i++) {
            int rrow = (t >> 3) + i * 128;
            __builtin_amdgcn_global_load_lds(
                (const __attribute__((address_space(1))) void*)
                    (vtb + (size_t)rrow * Nc + jt + schunk8),
                (__attribute__((address_space(3))) void*)
                    (vt_wbase + i * 128 * 64),
                16, 0, 0);
        }
        // stage ms (64 x 64 f32): 1 float4/thread, PREMASKED, swizzled dest
        {
            float4 v = *(const float4*)(mbase + (size_t)mrow * Nc + jt + mch * 4);
            v.x = (v.x <= thm) ? v.x : BIGF;
            v.y = (v.y <= thm) ? v.y : BIGF;
            v.z = (v.z <= thm) ? v.z : BIGF;
            v.w = (v.w <= thm) ? v.w : BIGF;
            *(float4*)&ms[msw] = v;
        }
        __syncthreads();

        const unsigned short* vb = &vt[(h * VDc) * 64];
        #pragma unroll
        for (int ks = 0; ks < 2; ks++) {
            float4 a0 = *(const float4*)&ms[ks ? a10 : a00];
            float4 a1 = *(const float4*)&ms[ks ? a11 : a01];
            float w0 = __builtin_amdgcn_exp2f(__builtin_fmaf(a0.x, cc, nmncc));
            float w1 = __builtin_amdgcn_exp2f(__builtin_fmaf(a0.y, cc, nmncc));
            float w2 = __builtin_amdgcn_exp2f(__builtin_fmaf(a0.z, cc, nmncc));
            float w3 = __builtin_amdgcn_exp2f(__builtin_fmaf(a0.w, cc, nmncc));
            float w4 = __builtin_amdgcn_exp2f(__builtin_fmaf(a1.x, cc, nmncc));
            float w5 = __builtin_amdgcn_exp2f(__builtin_fmaf(a1.y, cc, nmncc));
            float w6 = __builtin_amdgcn_exp2f(__builtin_fmaf(a1.z, cc, nmncc));
            float w7 = __builtin_amdgcn_exp2f(__builtin_fmaf(a1.w, cc, nmncc));
            zacc += ((w0 + w1) + (w2 + w3)) + ((w4 + w5) + (w6 + w7));
            union { s8v v; __hip_bfloat162 h2[4]; } afu;
            afu.h2[0] = __float22bfloat162_rn((float2){w0, w1});
            afu.h2[1] = __float22bfloat162_rn((float2){w2, w3});
            afu.h2[2] = __float22bfloat162_rn((float2){w4, w5});
            afu.h2[3] = __float22bfloat162_rn((float2){w6, w7});
            #pragma unroll
            for (int ct = 0; ct < 4; ct++) {
                int brow = ct * 16 + m16;
                s8v bf = *(const s8v*)(vb + brow * 64 + (((ks * 4 + q) ^ (m16 & 7)) << 3));
                acc[ct] = __builtin_amdgcn_mfma_f32_16x16x32_bf16(afu.v, bf, acc[ct], 0, 0, 0);
            }
        }
        __syncthreads();
    }

    // Z: lanes sharing m16 across q (xor 16, 32)
    zacc += __shfl_xor(zacc, 16);
    zacc += __shfl_xor(zacc, 32);
    if (q == 0)
        Zp[(((size_t)js * Bc + b) * Hc + h) * Nc + n0 + row] = zacc;

    // partial O: D row = q*4+rg (within the 16), col = ct*16+m16
    #pragma unroll
    for (int ct = 0; ct < 4; ct++) {
        #pragma unroll
        for (int rg = 0; rg < 4; rg++) {
            int nl = rq * 16 + q * 4 + rg;
            Op[(((size_t)js * Bc + b) * Nc + n0 + nl) * HIDc + h * VDc + ct * 16 + m16]
                = acc[ct][rg];
        }
    }
}

// ---------------------------------------------------------------------------
// K4: combine split-K partials, normalize, exact GELU. f32x4 per thread.
// grid = B*N*HID/1024 = 2048 blocks x 256.  (unchanged)
// ---------------------------------------------------------------------------
__global__ __launch_bounds__(256) void combine_kernel(
    const float* __restrict__ Op, const float* __restrict__ Zp,
    float* __restrict__ out, int S)
{
    int g = blockIdx.x * 256 + threadIdx.x;       // float4 index
    int c4 = g & 63;
    int n  = (g >> 6) & (Nc - 1);
    int b  = g >> 18;                             // 64 * 4096 = 2^18
    int h  = c4 >> 4;

    float z = 0.f;
    float4 v = {0.f, 0.f, 0.f, 0.f};
    for (int s = 0; s < S; s++) {
        z += Zp[(((size_t)s * Bc + b) * Hc + h) * Nc + n];
        float4 p = *(const float4*)&Op[(((size_t)s * Bc + b) * Nc + n) * HIDc + c4 * 4];
        v.x += p.x; v.y += p.y; v.z += p.z; v.w += p.w;
    }
    float iz = 1.0f / z;
    float4 o;
    float u;
    u = v.x * iz; o.x = 0.5f * u * (1.0f + erff(u * 0.7071067811865476f));
    u = v.y * iz; o.y = 0.5f * u * (1.0f + erff(u * 0.7071067811865476f));
    u = v.z * iz; o.z = 0.5f * u * (1.0f + erff(u * 0.7071067811865476f));
    u = v.w * iz; o.w = 0.5f * u * (1.0f + erff(u * 0.7071067811865476f));
    *(float4*)&out[(((size_t)b * Nc + n) * HIDc) + c4 * 4] = o;
}

// ---------------------------------------------------------------------------
extern "C" void kernel_launch(void* const* d_in, const int* in_sizes, int n_in,
                              void* d_out, int out_size, void* d_ws, size_t ws_size,
                              hipStream_t stream) {
    const float* m_dist = (const float*)d_in[0];
    const float* x      = (const float*)d_in[1];
    const float* r      = (const float*)d_in[2];
    const float* weight = (const float*)d_in[3];
    float* out = (float*)d_out;

    char* ws = (char*)d_ws;
    const size_t MB = 1024 * 1024;
    unsigned short* vt = (unsigned short*)ws;            // 4 MiB bf16 VT
    float* thr = (float*)(ws + 4 * MB);                  // 32 KiB
    float* mn  = (float*)(ws + 4 * MB + 32 * 1024);      // 32 KiB
    float* Zp  = (float*)(ws + 4 * MB + 64 * 1024);      // up to 512 KiB
    float* Op  = (float*)(ws + 5 * MB);                  // S * 8 MiB

    // split factor: prefer 4 (needs 37 MiB ws + 8.25 MiB prep), else 2, else 1
    int S = 4;
    if (ws_size < 14 * MB + 4 * (size_t)(Bc * Nc * HIDc * 4)) S = 2;
    if (ws_size < 14 * MB + 2 * (size_t)(Bc * Nc * HIDc * 4)) S = 1;
    int jlen = Nc / S;

    // prep buffers after Op
    char* pb = ws + 5 * MB + (size_t)S * (Bc * Nc * HIDc * 4);
    unsigned short* xh = (unsigned short*)pb;                       // 4 MiB
    unsigned short* xl = (unsigned short*)(pb + 4 * MB);            // 4 MiB
    unsigned short* wh = (unsigned short*)(pb + 8 * MB);            // 128 KiB
    unsigned short* wl = (unsigned short*)(pb + 8 * MB + 128 * 1024);

    prep_kernel<<<1152, 256, 0, stream>>>(x, weight, xh, xl, wh, wl);
    value_kernel<<<512, 256, 0, stream>>>(xh, xl, wh, wl, vt);
    thresh_kernel<<<Bc * Nc, 256, 0, stream>>>(m_dist, thr, mn);
    attn_kernel<<<S * Bc * (Nc / NT), 1024, 0, stream>>>(m_dist, r, vt, thr, mn, Op, Zp, jlen);
    combine_kernel<<<(Bc * Nc * HIDc) / 1024, 256, 0, stream>>>(Op, Zp, out, S);
}

// Round 3
// 266.391 us; speedup vs baseline: 1.0542x; 1.0016x over previous
//
#include <hip/hip_runtime.h>
#include <hip/hip_bf16.h>

// Problem constants
#define Bc   2
#define Nc   4096
#define Hc   4
#define HIDc 256
#define VDc  64

typedef short s8v  __attribute__((ext_vector_type(8)));
typedef float f4v  __attribute__((ext_vector_type(4)));

static __device__ __forceinline__ unsigned short bf16bits(float f) {
    __hip_bfloat16 h = __float2bfloat16(f);
    return *(unsigned short*)&h;
}

// ---------------------------------------------------------------------------
// K1 (fused): blocks 0..127 = W-prep (bf16 hi/lo split into MFMA-A-fragment-
// linear layout); blocks 128..8319 = per-row exact 30th percentile + row min.
// W-prep: elem = W[jc*32+(l>>4)*8+i][kt*16+(l&15)] stored at
//   ((h*4+kt)*8+jc)*512 + l*8 + i  (value_kernel reads one coalesced b128/lane)
// Thresh: windowed histogram on [0.25,0.35] (ranks 1228/1229 of U[0,1) rows
// land there with ~7 sigma margin); exact full-range fallback if not.
// ---------------------------------------------------------------------------
__global__ __launch_bounds__(256) void front_kernel(
    const float* __restrict__ m_dist, const float* __restrict__ wgt,
    unsigned short* __restrict__ wh, unsigned short* __restrict__ wl,
    float* __restrict__ thr_out, float* __restrict__ min_out)
{
    int t = threadIdx.x, bid = blockIdx.x;

    if (bid < 128) {
        int h  = bid >> 5;
        int kt = (bid >> 3) & 3;
        int jc = bid & 7;
        int lane = t >> 2, ii = t & 3;
        #pragma unroll
        for (int u = 0; u < 2; u++) {
            int i = ii * 2 + u;
            int j = jc * 32 + (lane >> 4) * 8 + i;
            int k = kt * 16 + (lane & 15);
            float v = wgt[((size_t)h * HIDc + j) * VDc + k];
            __hip_bfloat16 hb = __float2bfloat16(v);
            float hf = __bfloat162float(hb);
            size_t o = ((((size_t)h * 4 + kt) * 8 + jc) * 64 + lane) * 8 + i;
            wh[o] = *(unsigned short*)&hb;
            wl[o] = bf16bits(v - hf);
        }
        return;
    }

    __shared__ unsigned int hist[1024];
    __shared__ float wredf[4];
    __shared__ unsigned int wsum[4];
    __shared__ unsigned int wscan[4];
    __shared__ int b0s, b1s;
    __shared__ unsigned int c0s;
    __shared__ unsigned int ncand;
    __shared__ float cand[256];
    __shared__ float s0s, s1s;

    size_t rowid = bid - 128;
    const float* row = m_dist + rowid * Nc;

    float4 vals[4];
    float lmin = 1e30f;
    #pragma unroll
    for (int i = 0; i < 4; i++) {
        float4 v = ((const float4*)row)[t + i * 256];
        vals[i] = v;
        lmin = fminf(lmin, fminf(fminf(v.x, v.y), fminf(v.z, v.w)));
    }
    #pragma unroll
    for (int o = 32; o > 0; o >>= 1) lmin = fminf(lmin, __shfl_xor(lmin, o));
    if ((t & 63) == 0) wredf[t >> 6] = lmin;

    const unsigned int R0 = 1228u, R1 = 1229u;
    float wlo = 0.25f, whi = 0.35f;
    int b0 = 0, b1 = 0;
    unsigned int C0 = 0;

    for (;;) {
        float wscale = 1024.0f / (whi - wlo);

        for (int i = t; i < 1024; i += 256) hist[i] = 0u;
        if (t == 0) ncand = 0u;
        __syncthreads();

        unsigned int cb = 0;
        #pragma unroll
        for (int i = 0; i < 4; i++) {
            float a[4] = {vals[i].x, vals[i].y, vals[i].z, vals[i].w};
            #pragma unroll
            for (int j = 0; j < 4; j++) {
                float v = a[j];
                if (v < wlo) {
                    cb++;
                } else {
                    int bx = (int)((v - wlo) * wscale);
                    if (bx < 1024) atomicAdd(&hist[bx], 1u);
                }
            }
        }
        #pragma unroll
        for (int o = 32; o > 0; o >>= 1) cb += __shfl_xor(cb, o);
        if ((t & 63) == 0) wsum[t >> 6] = cb;
        __syncthreads();
        unsigned int Cb = wsum[0] + wsum[1] + wsum[2] + wsum[3];

        unsigned int c[4], csum = 0;
        #pragma unroll
        for (int j = 0; j < 4; j++) { c[j] = hist[t * 4 + j]; csum += c[j]; }
        unsigned int inc = csum;
        #pragma unroll
        for (int o = 1; o < 64; o <<= 1) {
            unsigned int nv = __shfl_up(inc, o);
            if ((t & 63) >= o) inc += nv;
        }
        if ((t & 63) == 63) wscan[t >> 6] = inc;
        __syncthreads();
        unsigned int wpref = 0;
        for (int wv = 0; wv < (t >> 6); wv++) wpref += wscan[wv];
        unsigned int T = wscan[0] + wscan[1] + wscan[2] + wscan[3];
        unsigned int P = Cb + wpref + inc - csum;

        unsigned int cum = P;
        #pragma unroll
        for (int j = 0; j < 4; j++) {
            unsigned int lo = cum, hi = cum + c[j];
            if (R0 >= lo && R0 < hi) { b0s = t * 4 + j; c0s = lo; }
            if (R1 >= lo && R1 < hi) { b1s = t * 4 + j; }
            cum = hi;
        }
        __syncthreads();

        if (Cb <= R0 && R1 < Cb + T) { b0 = b0s; b1 = b1s; C0 = c0s; break; }
        wlo = 0.0f; whi = 1.001f;
    }

    float wscale = 1024.0f / (whi - wlo);
    #pragma unroll
    for (int i = 0; i < 4; i++) {
        float a[4] = {vals[i].x, vals[i].y, vals[i].z, vals[i].w};
        #pragma unroll
        for (int j = 0; j < 4; j++) {
            float v = a[j];
            if (v >= wlo) {
                int bx = (int)((v - wlo) * wscale);
                if (bx >= b0 && bx <= b1) {
                    unsigned int p = atomicAdd(&ncand, 1u);
                    if (p < 256u) cand[p] = v;
                }
            }
        }
    }
    __syncthreads();
    unsigned int nc = min(ncand, 256u);
    if ((unsigned int)t < nc) {
        float v = cand[t];
        unsigned int rk = C0;
        for (unsigned int j = 0; j < nc; j++) {
            float u = cand[j];
            rk += (u < v || (u == v && j < (unsigned int)t)) ? 1u : 0u;
        }
        if (rk == R0) s0s = v;
        if (rk == R1) s1s = v;
    }
    __syncthreads();
    if (t == 0) {
        thr_out[rowid] = 0.5f * (s0s + s1s);
        min_out[rowid] = fminf(fminf(wredf[0], wredf[1]), fminf(wredf[2], wredf[3]));
    }
}

// ---------------------------------------------------------------------------
// K2: V^T via MFMA, 3-term bf16 split (Ah*Bh + Al*Bh + Ah*Bl ~ f32-accurate).
// R3: x converted f32 -> bf16 hi/lo INLINE (bit-identical to the old prep),
// removing the xh/xl 32 MB round-trip and the prep-x dispatch. No LDS.
// D[row=k][col=n] = sum_j W[j][k] * x[n][j]  ->  VT[b,h,k,n] bf16 directly.
// grid = B*H*(N/64) = 512 blocks x 256 (4 waves; wave w owns n-subtile w).
// ---------------------------------------------------------------------------
__global__ __launch_bounds__(256) void value_kernel(
    const float* __restrict__ x,
    const unsigned short* __restrict__ wh, const unsigned short* __restrict__ wl,
    unsigned short* __restrict__ vt_g)
{
    int t  = threadIdx.x;
    int bid = blockIdx.x;
    int nt = bid & 63;
    int h  = (bid >> 6) & 3;
    int b  = bid >> 8;
    int n0 = nt * 64;

    int w = t >> 6, lane = t & 63, q4 = lane >> 4, m16 = lane & 15;
    int nb = n0 + w * 16;

    const float* xp = x + ((size_t)(b * Nc + nb + m16)) * HIDc + q4 * 8;

    f4v acc[4];
    #pragma unroll
    for (int kt = 0; kt < 4; kt++) acc[kt] = (f4v){0.f, 0.f, 0.f, 0.f};

    #pragma unroll
    for (int jc = 0; jc < 8; jc++) {
        float4 xv0 = *(const float4*)(xp + jc * 32);
        float4 xv1 = *(const float4*)(xp + jc * 32 + 4);
        float f[8] = {xv0.x, xv0.y, xv0.z, xv0.w, xv1.x, xv1.y, xv1.z, xv1.w};
        union { s8v v; unsigned short u[8]; } hs, ls;
        #pragma unroll
        for (int i = 0; i < 8; i++) {
            __hip_bfloat16 hb = __float2bfloat16(f[i]);
            float hf = __bfloat162float(hb);
            hs.u[i] = *(unsigned short*)&hb;
            ls.u[i] = bf16bits(f[i] - hf);
        }
        #pragma unroll
        for (int kt = 0; kt < 4; kt++) {
            size_t ao = (((size_t)(h * 4 + kt) * 8 + jc) << 9) + lane * 8;
            s8v ah = *(const s8v*)(wh + ao);
            s8v al = *(const s8v*)(wl + ao);
            acc[kt] = __builtin_amdgcn_mfma_f32_16x16x32_bf16(ah, hs.v, acc[kt], 0, 0, 0);
            acc[kt] = __builtin_amdgcn_mfma_f32_16x16x32_bf16(al, hs.v, acc[kt], 0, 0, 0);
            acc[kt] = __builtin_amdgcn_mfma_f32_16x16x32_bf16(ah, ls.v, acc[kt], 0, 0, 0);
        }
    }

    unsigned short* vg = vt_g + (((size_t)b * Hc + h) * VDc) * Nc;
    #pragma unroll
    for (int kt = 0; kt < 4; kt++) {
        #pragma unroll
        for (int rg = 0; rg < 4; rg++) {
            int k = kt * 16 + q4 * 4 + rg;
            vg[(size_t)k * Nc + nb + m16] = bf16bits(acc[kt][rg]);
        }
    }
}

// ---------------------------------------------------------------------------
// K3: fused mask + softmax-numerator + PV (bf16 MFMA), split-K over j.
// NT=64, 1024 threads (16 waves: wave = (rowquad rq, head h)); 2 blocks/CU.
// vt staged by global_load_lds w/ source-side swizzle (linear LDS dest);
// ms staged via registers (fuses head-independent premask: masked d -> 3e38).
// R3: s_setprio(1) around the exp/MFMA cluster (T5 attn-regime: 2 independent
// blocks/CU at different phases -> scheduler favors the compute-phase wave).
// ---------------------------------------------------------------------------
#define NT 64
#define JT 64
#define BIGF 3.0e38f

__global__ __launch_bounds__(1024, 8) void attn_kernel(
    const float* __restrict__ m_dist, const float* __restrict__ rr,
    const unsigned short* __restrict__ vt_g,
    const float* __restrict__ thr_g, const float* __restrict__ min_g,
    float* __restrict__ Op, float* __restrict__ Zp, int jlen)
{
    __shared__ float ms[NT * 64];                 // 16 KB, chunk c at c^(row&15)
    __shared__ unsigned short vt[Hc * VDc * 64];  // 32 KB, chunk c at c^(row&7)

    int t = threadIdx.x;
    const int nblk = Bc * (Nc / NT);        // 128
    int js = blockIdx.x / nblk;
    int rb = blockIdx.x - js * nblk;
    int b  = rb >> 6;                       // Nc/NT = 64 row-tiles
    int n0 = (rb & 63) * NT;
    int j0 = js * jlen;

    int lane = t & 63, q = lane >> 4, m16 = lane & 15;
    int w = t >> 6;                         // wave 0..15
    int h = w & 3, rq = w >> 2;             // head, row-quad
    int row = rq * 16 + m16;                // local A-row this lane owns (0..63)

    float mn = min_g[b * Nc + n0 + row];
    float rv = rr[h];
    float cc = -(rv * rv) * 1.4426950408889634f;   // -r^2 * log2(e)
    float nmncc = -mn * cc;                        // w = exp2(fma(d, cc, nmncc))

    f4v acc[4];
    #pragma unroll
    for (int ct = 0; ct < 4; ct++) acc[ct] = (f4v){0.f, 0.f, 0.f, 0.f};
    float zacc = 0.f;

    const float* mbase = m_dist + ((size_t)b * Nc + n0) * Nc + j0;
    const unsigned short* vtb = vt_g + ((size_t)b * Hc * VDc) * Nc + j0;

    // ms staging map (swizzled LDS destination, register path w/ premask)
    int mrow = t >> 4, mch = t & 15;        // ms: 64 rows x 16 float4-chunks
    int msw  = mrow * 64 + ((mch ^ (mrow & 15)) << 2);
    float thm = thr_g[b * Nc + n0 + mrow];  // staging-row threshold (premask)

    // vt DMA staging map (2 DMA/thread): row r = (t>>3) + i*128, phys chunk t&7,
    // logical source chunk (t&7) ^ (r&7); r&7 == (t>>3)&7 (128 = 0 mod 8).
    int schunk8 = ((t & 7) ^ ((t >> 3) & 7)) * 8;   // ushort offset in row
    unsigned short* vt_wbase = &vt[(w * 8) * 64];   // uniform per wave

    // A-read swizzled chunk offsets for this lane (row&15 == m16)
    int a00 = row * 64 + (((q * 2 + 0) ^ m16) << 2);       // ks=0
    int a01 = row * 64 + (((q * 2 + 1) ^ m16) << 2);
    int a10 = row * 64 + (((8 + q * 2 + 0) ^ m16) << 2);   // ks=1
    int a11 = row * 64 + (((8 + q * 2 + 1) ^ m16) << 2);

    for (int jt = 0; jt < jlen; jt += JT) {
        // stage vt (256 rows x 64 j bf16): 2 x global_load_lds dwordx4 / thread
        #pragma unroll
        for (int i = 0; i < 2; i++) {
            int rrow = (t >> 3) + i * 128;
            __builtin_amdgcn_global_load_lds(
                (const __attribute__((address_space(1))) void*)
                    (vtb + (size_t)rrow * Nc + jt + schunk8),
                (__attribute__((address_space(3))) void*)
                    (vt_wbase + i * 128 * 64),
                16, 0, 0);
        }
        // stage ms (64 x 64 f32): 1 float4/thread, PREMASKED, swizzled dest
        {
            float4 v = *(const float4*)(mbase + (size_t)mrow * Nc + jt + mch * 4);
            v.x = (v.x <= thm) ? v.x : BIGF;
            v.y = (v.y <= thm) ? v.y : BIGF;
            v.z = (v.z <= thm) ? v.z : BIGF;
            v.w = (v.w <= thm) ? v.w : BIGF;
            *(float4*)&ms[msw] = v;
        }
        __syncthreads();

        __builtin_amdgcn_s_setprio(1);
        const unsigned short* vb = &vt[(h * VDc) * 64];
        #pragma unroll
        for (int ks = 0; ks < 2; ks++) {
            float4 a0 = *(const float4*)&ms[ks ? a10 : a00];
            float4 a1 = *(const float4*)&ms[ks ? a11 : a01];
            float w0 = __builtin_amdgcn_exp2f(__builtin_fmaf(a0.x, cc, nmncc));
            float w1 = __builtin_amdgcn_exp2f(__builtin_fmaf(a0.y, cc, nmncc));
            float w2 = __builtin_amdgcn_exp2f(__builtin_fmaf(a0.z, cc, nmncc));
            float w3 = __builtin_amdgcn_exp2f(__builtin_fmaf(a0.w, cc, nmncc));
            float w4 = __builtin_amdgcn_exp2f(__builtin_fmaf(a1.x, cc, nmncc));
            float w5 = __builtin_amdgcn_exp2f(__builtin_fmaf(a1.y, cc, nmncc));
            float w6 = __builtin_amdgcn_exp2f(__builtin_fmaf(a1.z, cc, nmncc));
            float w7 = __builtin_amdgcn_exp2f(__builtin_fmaf(a1.w, cc, nmncc));
            zacc += ((w0 + w1) + (w2 + w3)) + ((w4 + w5) + (w6 + w7));
            union { s8v v; __hip_bfloat162 h2[4]; } afu;
            afu.h2[0] = __float22bfloat162_rn((float2){w0, w1});
            afu.h2[1] = __float22bfloat162_rn((float2){w2, w3});
            afu.h2[2] = __float22bfloat162_rn((float2){w4, w5});
            afu.h2[3] = __float22bfloat162_rn((float2){w6, w7});
            #pragma unroll
            for (int ct = 0; ct < 4; ct++) {
                int brow = ct * 16 + m16;
                s8v bf = *(const s8v*)(vb + brow * 64 + (((ks * 4 + q) ^ (m16 & 7)) << 3));
                acc[ct] = __builtin_amdgcn_mfma_f32_16x16x32_bf16(afu.v, bf, acc[ct], 0, 0, 0);
            }
        }
        __builtin_amdgcn_s_setprio(0);
        __syncthreads();
    }

    // Z: lanes sharing m16 across q (xor 16, 32)
    zacc += __shfl_xor(zacc, 16);
    zacc += __shfl_xor(zacc, 32);
    if (q == 0)
        Zp[(((size_t)js * Bc + b) * Hc + h) * Nc + n0 + row] = zacc;

    // partial O: D row = q*4+rg (within the 16), col = ct*16+m16
    #pragma unroll
    for (int ct = 0; ct < 4; ct++) {
        #pragma unroll
        for (int rg = 0; rg < 4; rg++) {
            int nl = rq * 16 + q * 4 + rg;
            Op[(((size_t)js * Bc + b) * Nc + n0 + nl) * HIDc + h * VDc + ct * 16 + m16]
                = acc[ct][rg];
        }
    }
}

// ---------------------------------------------------------------------------
// K4: combine split-K partials, normalize, exact GELU. f32x4 per thread.
// grid = B*N*HID/1024 = 2048 blocks x 256.  (unchanged)
// ---------------------------------------------------------------------------
__global__ __launch_bounds__(256) void combine_kernel(
    const float* __restrict__ Op, const float* __restrict__ Zp,
    float* __restrict__ out, int S)
{
    int g = blockIdx.x * 256 + threadIdx.x;       // float4 index
    int c4 = g & 63;
    int n  = (g >> 6) & (Nc - 1);
    int b  = g >> 18;                             // 64 * 4096 = 2^18
    int h  = c4 >> 4;

    float z = 0.f;
    float4 v = {0.f, 0.f, 0.f, 0.f};
    for (int s = 0; s < S; s++) {
        z += Zp[(((size_t)s * Bc + b) * Hc + h) * Nc + n];
        float4 p = *(const float4*)&Op[(((size_t)s * Bc + b) * Nc + n) * HIDc + c4 * 4];
        v.x += p.x; v.y += p.y; v.z += p.z; v.w += p.w;
    }
    float iz = 1.0f / z;
    float4 o;
    float u;
    u = v.x * iz; o.x = 0.5f * u * (1.0f + erff(u * 0.7071067811865476f));
    u = v.y * iz; o.y = 0.5f * u * (1.0f + erff(u * 0.7071067811865476f));
    u = v.z * iz; o.z = 0.5f * u * (1.0f + erff(u * 0.7071067811865476f));
    u = v.w * iz; o.w = 0.5f * u * (1.0f + erff(u * 0.7071067811865476f));
    *(float4*)&out[(((size_t)b * Nc + n) * HIDc) + c4 * 4] = o;
}

// ---------------------------------------------------------------------------
extern "C" void kernel_launch(void* const* d_in, const int* in_sizes, int n_in,
                              void* d_out, int out_size, void* d_ws, size_t ws_size,
                              hipStream_t stream) {
    const float* m_dist = (const float*)d_in[0];
    const float* x      = (const float*)d_in[1];
    const float* r      = (const float*)d_in[2];
    const float* weight = (const float*)d_in[3];
    float* out = (float*)d_out;

    char* ws = (char*)d_ws;
    const size_t MB = 1024 * 1024;
    unsigned short* vt = (unsigned short*)ws;            // 4 MiB bf16 VT
    float* thr = (float*)(ws + 4 * MB);                  // 32 KiB
    float* mn  = (float*)(ws + 4 * MB + 32 * 1024);      // 32 KiB
    float* Zp  = (float*)(ws + 4 * MB + 64 * 1024);      // up to 512 KiB
    float* Op  = (float*)(ws + 5 * MB);                  // S * 8 MiB

    const size_t OpSz = (size_t)Bc * Nc * HIDc * 4;      // 8 MiB
    // split factor: prefer 4, else 2, else 1 (needs 5MB + S*OpSz + 256KB)
    int S = 4;
    if (ws_size < 6 * MB + 4 * OpSz) S = 2;
    if (ws_size < 6 * MB + 2 * OpSz) S = 1;
    int jlen = Nc / S;

    // W hi/lo fragment buffers after Op (128 KiB each)
    char* pb = ws + 5 * MB + (size_t)S * OpSz;
    unsigned short* wh = (unsigned short*)pb;
    unsigned short* wl = (unsigned short*)(pb + 128 * 1024);

    front_kernel<<<128 + Bc * Nc, 256, 0, stream>>>(m_dist, weight, wh, wl, thr, mn);
    value_kernel<<<512, 256, 0, stream>>>(x, wh, wl, vt);
    attn_kernel<<<S * Bc * (Nc / NT), 1024, 0, stream>>>(m_dist, r, vt, thr, mn, Op, Zp, jlen);
    combine_kernel<<<(Bc * Nc * HIDc) / 1024, 256, 0, stream>>>(Op, Zp, out, S);
}

// Round 4
// 262.634 us; speedup vs baseline: 1.0693x; 1.0143x over previous
//
#include <hip/hip_runtime.h>
#include <hip/hip_bf16.h>

// Problem constants
#define Bc   2
#define Nc   4096
#define Hc   4
#define HIDc 256
#define VDc  64

typedef short s8v  __attribute__((ext_vector_type(8)));
typedef float f4v  __attribute__((ext_vector_type(4)));

static __device__ __forceinline__ unsigned short bf16bits(float f) {
    __hip_bfloat16 h = __float2bfloat16(f);
    return *(unsigned short*)&h;
}

// ---------------------------------------------------------------------------
// K1 (fused): blocks 0..127 = W-prep (bf16 hi/lo split into MFMA-A-fragment-
// linear layout); blocks 128..8319 = per-row exact 30th percentile + row min.
// Thresh: windowed histogram on [0.25,0.35] (ranks 1228/1229 of U[0,1) rows
// land there with ~7 sigma margin); exact full-range fallback if not.
// ---------------------------------------------------------------------------
__global__ __launch_bounds__(256) void front_kernel(
    const float* __restrict__ m_dist, const float* __restrict__ wgt,
    unsigned short* __restrict__ wh, unsigned short* __restrict__ wl,
    float* __restrict__ thr_out, float* __restrict__ min_out)
{
    int t = threadIdx.x, bid = blockIdx.x;

    if (bid < 128) {
        int h  = bid >> 5;
        int kt = (bid >> 3) & 3;
        int jc = bid & 7;
        int lane = t >> 2, ii = t & 3;
        #pragma unroll
        for (int u = 0; u < 2; u++) {
            int i = ii * 2 + u;
            int j = jc * 32 + (lane >> 4) * 8 + i;
            int k = kt * 16 + (lane & 15);
            float v = wgt[((size_t)h * HIDc + j) * VDc + k];
            __hip_bfloat16 hb = __float2bfloat16(v);
            float hf = __bfloat162float(hb);
            size_t o = ((((size_t)h * 4 + kt) * 8 + jc) * 64 + lane) * 8 + i;
            wh[o] = *(unsigned short*)&hb;
            wl[o] = bf16bits(v - hf);
        }
        return;
    }

    __shared__ unsigned int hist[1024];
    __shared__ float wredf[4];
    __shared__ unsigned int wsum[4];
    __shared__ unsigned int wscan[4];
    __shared__ int b0s, b1s;
    __shared__ unsigned int c0s;
    __shared__ unsigned int ncand;
    __shared__ float cand[256];
    __shared__ float s0s, s1s;

    size_t rowid = bid - 128;
    const float* row = m_dist + rowid * Nc;

    float4 vals[4];
    float lmin = 1e30f;
    #pragma unroll
    for (int i = 0; i < 4; i++) {
        float4 v = ((const float4*)row)[t + i * 256];
        vals[i] = v;
        lmin = fminf(lmin, fminf(fminf(v.x, v.y), fminf(v.z, v.w)));
    }
    #pragma unroll
    for (int o = 32; o > 0; o >>= 1) lmin = fminf(lmin, __shfl_xor(lmin, o));
    if ((t & 63) == 0) wredf[t >> 6] = lmin;

    const unsigned int R0 = 1228u, R1 = 1229u;
    float wlo = 0.25f, whi = 0.35f;
    int b0 = 0, b1 = 0;
    unsigned int C0 = 0;

    for (;;) {
        float wscale = 1024.0f / (whi - wlo);

        for (int i = t; i < 1024; i += 256) hist[i] = 0u;
        if (t == 0) ncand = 0u;
        __syncthreads();

        unsigned int cb = 0;
        #pragma unroll
        for (int i = 0; i < 4; i++) {
            float a[4] = {vals[i].x, vals[i].y, vals[i].z, vals[i].w};
            #pragma unroll
            for (int j = 0; j < 4; j++) {
                float v = a[j];
                if (v < wlo) {
                    cb++;
                } else {
                    int bx = (int)((v - wlo) * wscale);
                    if (bx < 1024) atomicAdd(&hist[bx], 1u);
                }
            }
        }
        #pragma unroll
        for (int o = 32; o > 0; o >>= 1) cb += __shfl_xor(cb, o);
        if ((t & 63) == 0) wsum[t >> 6] = cb;
        __syncthreads();
        unsigned int Cb = wsum[0] + wsum[1] + wsum[2] + wsum[3];

        unsigned int c[4], csum = 0;
        #pragma unroll
        for (int j = 0; j < 4; j++) { c[j] = hist[t * 4 + j]; csum += c[j]; }
        unsigned int inc = csum;
        #pragma unroll
        for (int o = 1; o < 64; o <<= 1) {
            unsigned int nv = __shfl_up(inc, o);
            if ((t & 63) >= o) inc += nv;
        }
        if ((t & 63) == 63) wscan[t >> 6] = inc;
        __syncthreads();
        unsigned int wpref = 0;
        for (int wv = 0; wv < (t >> 6); wv++) wpref += wscan[wv];
        unsigned int T = wscan[0] + wscan[1] + wscan[2] + wscan[3];
        unsigned int P = Cb + wpref + inc - csum;

        unsigned int cum = P;
        #pragma unroll
        for (int j = 0; j < 4; j++) {
            unsigned int lo = cum, hi = cum + c[j];
            if (R0 >= lo && R0 < hi) { b0s = t * 4 + j; c0s = lo; }
            if (R1 >= lo && R1 < hi) { b1s = t * 4 + j; }
            cum = hi;
        }
        __syncthreads();

        if (Cb <= R0 && R1 < Cb + T) { b0 = b0s; b1 = b1s; C0 = c0s; break; }
        wlo = 0.0f; whi = 1.001f;
    }

    float wscale = 1024.0f / (whi - wlo);
    #pragma unroll
    for (int i = 0; i < 4; i++) {
        float a[4] = {vals[i].x, vals[i].y, vals[i].z, vals[i].w};
        #pragma unroll
        for (int j = 0; j < 4; j++) {
            float v = a[j];
            if (v >= wlo) {
                int bx = (int)((v - wlo) * wscale);
                if (bx >= b0 && bx <= b1) {
                    unsigned int p = atomicAdd(&ncand, 1u);
                    if (p < 256u) cand[p] = v;
                }
            }
        }
    }
    __syncthreads();
    unsigned int nc = min(ncand, 256u);
    if ((unsigned int)t < nc) {
        float v = cand[t];
        unsigned int rk = C0;
        for (unsigned int j = 0; j < nc; j++) {
            float u = cand[j];
            rk += (u < v || (u == v && j < (unsigned int)t)) ? 1u : 0u;
        }
        if (rk == R0) s0s = v;
        if (rk == R1) s1s = v;
    }
    __syncthreads();
    if (t == 0) {
        thr_out[rowid] = 0.5f * (s0s + s1s);
        min_out[rowid] = fminf(fminf(wredf[0], wredf[1]), fminf(wredf[2], wredf[3]));
    }
}

// ---------------------------------------------------------------------------
// K2: V^T via MFMA, 3-term bf16 split (Ah*Bh + Al*Bh + Ah*Bl ~ f32-accurate).
// x converted f32 -> bf16 hi/lo inline. VT[b,h,k,n] bf16 directly.
// grid = B*H*(N/64) = 512 blocks x 256 (4 waves; wave w owns n-subtile w).
// ---------------------------------------------------------------------------
__global__ __launch_bounds__(256) void value_kernel(
    const float* __restrict__ x,
    const unsigned short* __restrict__ wh, const unsigned short* __restrict__ wl,
    unsigned short* __restrict__ vt_g)
{
    int t  = threadIdx.x;
    int bid = blockIdx.x;
    int nt = bid & 63;
    int h  = (bid >> 6) & 3;
    int b  = bid >> 8;
    int n0 = nt * 64;

    int w = t >> 6, lane = t & 63, q4 = lane >> 4, m16 = lane & 15;
    int nb = n0 + w * 16;

    const float* xp = x + ((size_t)(b * Nc + nb + m16)) * HIDc + q4 * 8;

    f4v acc[4];
    #pragma unroll
    for (int kt = 0; kt < 4; kt++) acc[kt] = (f4v){0.f, 0.f, 0.f, 0.f};

    #pragma unroll
    for (int jc = 0; jc < 8; jc++) {
        float4 xv0 = *(const float4*)(xp + jc * 32);
        float4 xv1 = *(const float4*)(xp + jc * 32 + 4);
        float f[8] = {xv0.x, xv0.y, xv0.z, xv0.w, xv1.x, xv1.y, xv1.z, xv1.w};
        union { s8v v; unsigned short u[8]; } hs, ls;
        #pragma unroll
        for (int i = 0; i < 8; i++) {
            __hip_bfloat16 hb = __float2bfloat16(f[i]);
            float hf = __bfloat162float(hb);
            hs.u[i] = *(unsigned short*)&hb;
            ls.u[i] = bf16bits(f[i] - hf);
        }
        #pragma unroll
        for (int kt = 0; kt < 4; kt++) {
            size_t ao = (((size_t)(h * 4 + kt) * 8 + jc) << 9) + lane * 8;
            s8v ah = *(const s8v*)(wh + ao);
            s8v al = *(const s8v*)(wl + ao);
            acc[kt] = __builtin_amdgcn_mfma_f32_16x16x32_bf16(ah, hs.v, acc[kt], 0, 0, 0);
            acc[kt] = __builtin_amdgcn_mfma_f32_16x16x32_bf16(al, hs.v, acc[kt], 0, 0, 0);
            acc[kt] = __builtin_amdgcn_mfma_f32_16x16x32_bf16(ah, ls.v, acc[kt], 0, 0, 0);
        }
    }

    unsigned short* vg = vt_g + (((size_t)b * Hc + h) * VDc) * Nc;
    #pragma unroll
    for (int kt = 0; kt < 4; kt++) {
        #pragma unroll
        for (int rg = 0; rg < 4; rg++) {
            int k = kt * 16 + q4 * 4 + rg;
            vg[(size_t)k * Nc + nb + m16] = bf16bits(acc[kt][rg]);
        }
    }
}

// ---------------------------------------------------------------------------
// K3: fused mask + softmax-numerator + PV (bf16 MFMA), split-K over j.
// R4: software-pipelined 2-phase loop (T14/T3 minimum form):
//   JT 64->32, DOUBLE-BUFFERED ms and vt (still 48 KB total -> 2 blocks/CU),
//   ONE barrier per iteration, loads for step i+1 issued right after the
//   barrier so they complete under compute(i). The compiler's pre-barrier
//   vmcnt(0) drain is harmless: at the barrier the only outstanding loads
//   were issued a full compute-phase earlier. setprio REMOVED (lockstep
//   regime = m190 null/negative; suspected cause of R3's 155us cold attn).
// Race-freedom: buf[p^1] is DMA-overwritten only after the barrier that
// guarantees all waves finished compute(i-1) (its last reader); ms(i) is
// ds_written before that same barrier; compute(i) reads after it.
// MFMA j-order identical to R3 -> acc bit-identical; zacc tree differs ~1ulp.
// ---------------------------------------------------------------------------
#define NT 64
#define JT 32
#define BIGF 3.0e38f

__global__ __launch_bounds__(1024, 8) void attn_kernel(
    const float* __restrict__ m_dist, const float* __restrict__ rr,
    const unsigned short* __restrict__ vt_g,
    const float* __restrict__ thr_g, const float* __restrict__ min_g,
    float* __restrict__ Op, float* __restrict__ Zp, int jlen)
{
    __shared__ float ms[2][NT * JT];                  // 2 x 8 KB, f4-chunk c at c^(row&7)
    __shared__ unsigned short vt[2][Hc * VDc * JT];   // 2 x 16 KB, 16B-chunk c at c^(row&3)

    int t = threadIdx.x;
    const int nblk = Bc * (Nc / NT);        // 128
    int js = blockIdx.x / nblk;
    int rb = blockIdx.x - js * nblk;
    int b  = rb >> 6;                       // Nc/NT = 64 row-tiles
    int n0 = (rb & 63) * NT;
    int j0 = js * jlen;

    int lane = t & 63, q = lane >> 4, m16 = lane & 15;
    int w = t >> 6;                         // wave 0..15
    int h = w & 3, rq = w >> 2;             // head, row-quad
    int row = rq * 16 + m16;                // local A-row this lane owns (0..63)

    float mn = min_g[b * Nc + n0 + row];
    float rv = rr[h];
    float cc = -(rv * rv) * 1.4426950408889634f;   // -r^2 * log2(e)
    float nmncc = -mn * cc;                        // w = exp2(fma(d, cc, nmncc))

    f4v acc[4];
    #pragma unroll
    for (int ct = 0; ct < 4; ct++) acc[ct] = (f4v){0.f, 0.f, 0.f, 0.f};
    float zacc = 0.f;

    const float* mbase = m_dist + ((size_t)b * Nc + n0) * Nc + j0;
    const unsigned short* vtb = vt_g + ((size_t)b * Hc * VDc) * Nc + j0;

    // ms staging (threads 0..511 / waves 0..7): row t>>3, logical f4-chunk t&7
    int mrow = t >> 3, mch = t & 7;
    int msw  = mrow * JT + ((mch ^ (mrow & 7)) << 2);
    const float* msrc = mbase + (size_t)mrow * Nc + mch * 4;
    float thm = (t < 512) ? thr_g[b * Nc + n0 + mrow] : 0.f;

    // vt DMA staging (all threads): row t>>2, logical 16B-chunk (t&3)^(row&3);
    // LDS dest linear = t*16 bytes (wave-uniform base + lane*16).
    int vrow = t >> 2;
    int vlc  = (t & 3) ^ (vrow & 3);
    const unsigned short* vsrc = vtb + (size_t)vrow * Nc + vlc * 8;

    // A-read swizzled f4-chunk offsets (row&7 == m16&7)
    int s7 = m16 & 7;
    int a0o = row * JT + (((q * 2 + 0) ^ s7) << 2);
    int a1o = row * JT + (((q * 2 + 1) ^ s7) << 2);
    // B-read swizzled 16B-chunk (ushort offset within row); brow&3 == m16&3
    int bco = (q ^ (m16 & 3)) << 3;

    int niter = jlen / JT;

    // prologue: issue loads for it=0
    float4 msreg;
    if (t < 512) msreg = *(const float4*)(msrc);
    __builtin_amdgcn_global_load_lds(
        (const __attribute__((address_space(1))) void*)(vsrc),
        (__attribute__((address_space(3))) void*)(&vt[0][(size_t)t * 8]),
        16, 0, 0);

    int cur = 0;
    for (int it = 0; it < niter; ++it) {
        // write ms(it) into buf cur (premask; masked d -> 3e38 so exp2 -> 0)
        if (t < 512) {
            float4 v = msreg;
            v.x = (v.x <= thm) ? v.x : BIGF;
            v.y = (v.y <= thm) ? v.y : BIGF;
            v.z = (v.z <= thm) ? v.z : BIGF;
            v.w = (v.w <= thm) ? v.w : BIGF;
            *(float4*)&ms[cur][msw] = v;
        }
        __syncthreads();   // vt(it) DMA drained + ms(it) visible; buf cur^1 free

        // issue loads for it+1 into buf cur^1 (complete under compute below)
        if (it + 1 < niter) {
            int jn = (it + 1) * JT;
            if (t < 512) msreg = *(const float4*)(msrc + jn);
            __builtin_amdgcn_global_load_lds(
                (const __attribute__((address_space(1))) void*)(vsrc + jn),
                (__attribute__((address_space(3))) void*)(&vt[cur ^ 1][(size_t)t * 8]),
                16, 0, 0);
        }

        // compute(it) from buf cur
        const unsigned short* vb = &vt[cur][h * VDc * JT];
        float4 a0 = *(const float4*)&ms[cur][a0o];
        float4 a1 = *(const float4*)&ms[cur][a1o];
        float w0 = __builtin_amdgcn_exp2f(__builtin_fmaf(a0.x, cc, nmncc));
        float w1 = __builtin_amdgcn_exp2f(__builtin_fmaf(a0.y, cc, nmncc));
        float w2 = __builtin_amdgcn_exp2f(__builtin_fmaf(a0.z, cc, nmncc));
        float w3 = __builtin_amdgcn_exp2f(__builtin_fmaf(a0.w, cc, nmncc));
        float w4 = __builtin_amdgcn_exp2f(__builtin_fmaf(a1.x, cc, nmncc));
        float w5 = __builtin_amdgcn_exp2f(__builtin_fmaf(a1.y, cc, nmncc));
        float w6 = __builtin_amdgcn_exp2f(__builtin_fmaf(a1.z, cc, nmncc));
        float w7 = __builtin_amdgcn_exp2f(__builtin_fmaf(a1.w, cc, nmncc));
        zacc += ((w0 + w1) + (w2 + w3)) + ((w4 + w5) + (w6 + w7));
        union { s8v v; __hip_bfloat162 h2[4]; } afu;
        afu.h2[0] = __float22bfloat162_rn((float2){w0, w1});
        afu.h2[1] = __float22bfloat162_rn((float2){w2, w3});
        afu.h2[2] = __float22bfloat162_rn((float2){w4, w5});
        afu.h2[3] = __float22bfloat162_rn((float2){w6, w7});
        #pragma unroll
        for (int ct = 0; ct < 4; ct++) {
            int brow = ct * 16 + m16;
            s8v bf = *(const s8v*)(vb + brow * JT + bco);
            acc[ct] = __builtin_amdgcn_mfma_f32_16x16x32_bf16(afu.v, bf, acc[ct], 0, 0, 0);
        }
        cur ^= 1;
    }

    // Z: lanes sharing m16 across q (xor 16, 32)
    zacc += __shfl_xor(zacc, 16);
    zacc += __shfl_xor(zacc, 32);
    if (q == 0)
        Zp[(((size_t)js * Bc + b) * Hc + h) * Nc + n0 + row] = zacc;

    // partial O: D row = q*4+rg (within the 16), col = ct*16+m16
    #pragma unroll
    for (int ct = 0; ct < 4; ct++) {
        #pragma unroll
        for (int rg = 0; rg < 4; rg++) {
            int nl = rq * 16 + q * 4 + rg;
            Op[(((size_t)js * Bc + b) * Nc + n0 + nl) * HIDc + h * VDc + ct * 16 + m16]
                = acc[ct][rg];
        }
    }
}

// ---------------------------------------------------------------------------
// K4: combine split-K partials, normalize, exact GELU. f32x4 per thread.
// grid = B*N*HID/1024 = 2048 blocks x 256.  (unchanged)
// ---------------------------------------------------------------------------
__global__ __launch_bounds__(256) void combine_kernel(
    const float* __restrict__ Op, const float* __restrict__ Zp,
    float* __restrict__ out, int S)
{
    int g = blockIdx.x * 256 + threadIdx.x;       // float4 index
    int c4 = g & 63;
    int n  = (g >> 6) & (Nc - 1);
    int b  = g >> 18;                             // 64 * 4096 = 2^18
    int h  = c4 >> 4;

    float z = 0.f;
    float4 v = {0.f, 0.f, 0.f, 0.f};
    for (int s = 0; s < S; s++) {
        z += Zp[(((size_t)s * Bc + b) * Hc + h) * Nc + n];
        float4 p = *(const float4*)&Op[(((size_t)s * Bc + b) * Nc + n) * HIDc + c4 * 4];
        v.x += p.x; v.y += p.y; v.z += p.z; v.w += p.w;
    }
    float iz = 1.0f / z;
    float4 o;
    float u;
    u = v.x * iz; o.x = 0.5f * u * (1.0f + erff(u * 0.7071067811865476f));
    u = v.y * iz; o.y = 0.5f * u * (1.0f + erff(u * 0.7071067811865476f));
    u = v.z * iz; o.z = 0.5f * u * (1.0f + erff(u * 0.7071067811865476f));
    u = v.w * iz; o.w = 0.5f * u * (1.0f + erff(u * 0.7071067811865476f));
    *(float4*)&out[(((size_t)b * Nc + n) * HIDc) + c4 * 4] = o;
}

// ---------------------------------------------------------------------------
extern "C" void kernel_launch(void* const* d_in, const int* in_sizes, int n_in,
                              void* d_out, int out_size, void* d_ws, size_t ws_size,
                              hipStream_t stream) {
    const float* m_dist = (const float*)d_in[0];
    const float* x      = (const float*)d_in[1];
    const float* r      = (const float*)d_in[2];
    const float* weight = (const float*)d_in[3];
    float* out = (float*)d_out;

    char* ws = (char*)d_ws;
    const size_t MB = 1024 * 1024;
    unsigned short* vt = (unsigned short*)ws;            // 4 MiB bf16 VT
    float* thr = (float*)(ws + 4 * MB);                  // 32 KiB
    float* mn  = (float*)(ws + 4 * MB + 32 * 1024);      // 32 KiB
    float* Zp  = (float*)(ws + 4 * MB + 64 * 1024);      // up to 512 KiB
    float* Op  = (float*)(ws + 5 * MB);                  // S * 8 MiB

    const size_t OpSz = (size_t)Bc * Nc * HIDc * 4;      // 8 MiB
    // split factor: prefer 4, else 2, else 1 (needs 5MB + S*OpSz + 256KB)
    int S = 4;
    if (ws_size < 6 * MB + 4 * OpSz) S = 2;
    if (ws_size < 6 * MB + 2 * OpSz) S = 1;
    int jlen = Nc / S;

    // W hi/lo fragment buffers after Op (128 KiB each)
    char* pb = ws + 5 * MB + (size_t)S * OpSz;
    unsigned short* wh = (unsigned short*)pb;
    unsigned short* wl = (unsigned short*)(pb + 128 * 1024);

    front_kernel<<<128 + Bc * Nc, 256, 0, stream>>>(m_dist, weight, wh, wl, thr, mn);
    value_kernel<<<512, 256, 0, stream>>>(x, wh, wl, vt);
    attn_kernel<<<S * Bc * (Nc / NT), 1024, 0, stream>>>(m_dist, r, vt, thr, mn, Op, Zp, jlen);
    combine_kernel<<<(Bc * Nc * HIDc) / 1024, 256, 0, stream>>>(Op, Zp, out, S);
}